// Round 1
// baseline (374.653 us; speedup 1.0000x reference)
//
#include <hip/hip_runtime.h>
#include <hip/hip_bf16.h>

// Problem: SpotlightLoss. pred/target f32, shape (4,2,16,512,512).
// R = 8 channels, each 2^22 = 4194304 contiguous elements.
// Pipeline: init -> minmax(target) -> hist(target) -> otsu -> main(pred,target) -> finalize.

#define CH 8
#define CH_SHIFT 22
#define CH_ELEMS (1 << CH_SHIFT)          // 4194304
#define BPC 256                            // blocks per channel
#define BLK_ELEMS (CH_ELEMS / BPC)         // 16384 elements / block
#define NB 256                             // histogram bins
#define K_SIG (-0.95f)
#define EPS_F 1e-6

// ---- monotonic float<->uint mapping for atomic min/max ----
__device__ __forceinline__ unsigned mapF(float f) {
    unsigned u = __float_as_uint(f);
    return (u & 0x80000000u) ? ~u : (u | 0x80000000u);
}
__device__ __forceinline__ float unmapF(unsigned m) {
    unsigned u = (m & 0x80000000u) ? (m ^ 0x80000000u) : ~m;
    return __uint_as_float(u);
}

__global__ void k_init(unsigned* __restrict__ minM, unsigned* __restrict__ maxM,
                       unsigned* __restrict__ hist, double* __restrict__ acc) {
    int i = threadIdx.x + blockIdx.x * blockDim.x;
    if (i < CH) { minM[i] = 0xFFFFFFFFu; maxM[i] = 0u; }
    if (i < CH * NB) hist[i] = 0u;
    if (i < CH * 5) acc[i] = 0.0;
}

__global__ __launch_bounds__(256) void k_minmax(const float* __restrict__ t,
                                                unsigned* __restrict__ minM,
                                                unsigned* __restrict__ maxM) {
    const int ch = blockIdx.x >> 8;       // / BPC
    const int blk = blockIdx.x & (BPC - 1);
    const float4* p = (const float4*)(t + ((size_t)ch << CH_SHIFT) + (size_t)blk * BLK_ELEMS);
    float lo = INFINITY, hi = -INFINITY;
    for (int it = 0; it < BLK_ELEMS / (256 * 4); ++it) {
        float4 v = p[it * 256 + threadIdx.x];
        lo = fminf(lo, fminf(fminf(v.x, v.y), fminf(v.z, v.w)));
        hi = fmaxf(hi, fmaxf(fmaxf(v.x, v.y), fmaxf(v.z, v.w)));
    }
    for (int off = 32; off; off >>= 1) {
        lo = fminf(lo, __shfl_down(lo, off));
        hi = fmaxf(hi, __shfl_down(hi, off));
    }
    __shared__ float slo[4], shi[4];
    const int wave = threadIdx.x >> 6, lane = threadIdx.x & 63;
    if (lane == 0) { slo[wave] = lo; shi[wave] = hi; }
    __syncthreads();
    if (threadIdx.x == 0) {
        lo = fminf(fminf(slo[0], slo[1]), fminf(slo[2], slo[3]));
        hi = fmaxf(fmaxf(shi[0], shi[1]), fmaxf(shi[2], shi[3]));
        atomicMin(&minM[ch], mapF(lo));
        atomicMax(&maxM[ch], mapF(hi));
    }
}

__global__ __launch_bounds__(256) void k_hist(const float* __restrict__ t,
                                              const unsigned* __restrict__ minM,
                                              const unsigned* __restrict__ maxM,
                                              unsigned* __restrict__ hist) {
    __shared__ unsigned h[4][NB];          // per-wave private histograms
    for (int i = threadIdx.x; i < 4 * NB; i += 256) ((unsigned*)h)[i] = 0u;
    __syncthreads();
    const int ch = blockIdx.x >> 8;
    const int blk = blockIdx.x & (BPC - 1);
    const int wave = threadIdx.x >> 6;
    const float lo = unmapF(minM[ch]);
    const float hi = unmapF(maxM[ch]);
    const float span = hi - lo;
    const float safe = (span > 0.0f) ? span : 1.0f;
    const float4* p = (const float4*)(t + ((size_t)ch << CH_SHIFT) + (size_t)blk * BLK_ELEMS);
    for (int it = 0; it < BLK_ELEMS / (256 * 4); ++it) {
        float4 v = p[it * 256 + threadIdx.x];
        float x[4] = {v.x, v.y, v.z, v.w};
        for (int j = 0; j < 4; ++j) {
            // exact reference arithmetic: ((x - lo) / safe_span) * 256, trunc, clip
            float fi = (x[j] - lo) / safe * 256.0f;
            int b = (int)fi;
            b = b < 0 ? 0 : (b > NB - 1 ? NB - 1 : b);
            atomicAdd(&h[wave][b], 1u);
        }
    }
    __syncthreads();
    // flush: thread tid handles bin tid
    unsigned s = h[0][threadIdx.x] + h[1][threadIdx.x] + h[2][threadIdx.x] + h[3][threadIdx.x];
    if (s) atomicAdd(&hist[ch * NB + threadIdx.x], s);
}

__global__ void k_otsu(const unsigned* __restrict__ hist,
                       const unsigned* __restrict__ minM,
                       const unsigned* __restrict__ maxM,
                       float* __restrict__ thr) {
    int ch = threadIdx.x;
    if (ch >= CH) return;
    const float lo = unmapF(minM[ch]);
    const float hi = unmapF(maxM[ch]);
    const float span = hi - lo;
    const unsigned* h = hist + ch * NB;
    // global mean and total (sequential f32, matches cumsum[-1])
    float total = 0.0f, gm = 0.0f;
    for (int i = 0; i < NB; ++i) {
        float e0 = lo + span * ((float)i / 256.0f);
        float e1 = lo + span * ((float)(i + 1) / 256.0f);
        float c = (e0 + e1) * 0.5f;
        float hv = (float)h[i];
        total += hv;
        gm += hv * c;
    }
    float cs = 0.0f, cm = 0.0f, best = -INFINITY, bestC = lo;
    for (int i = 0; i < NB; ++i) {
        float e0 = lo + span * ((float)i / 256.0f);
        float e1 = lo + span * ((float)(i + 1) / 256.0f);
        float c = (e0 + e1) * 0.5f;
        float hv = (float)h[i];
        cs += hv;
        cm += hv * c;
        float num = cm * total - gm * cs;
        float iv = num * num / (cs * (total - cs) + 1e-10f);
        if (iv > best) { best = iv; bestC = c; }   // first-occurrence argmax
    }
    thr[ch] = (span > 0.0f) ? bestC : lo;
}

__device__ __forceinline__ float soft_sig(float x) {
    // raw = (x - k*x) / (k - 2*k*|x| + 1), clip [0,1]; k = -0.95
    float ax = fabsf(x);
    float num = x - K_SIG * x;
    float den = (K_SIG - 2.0f * K_SIG * ax) + 1.0f;
    float raw = num / den;
    return fminf(fmaxf(raw, 0.0f), 1.0f);
}

__global__ __launch_bounds__(256) void k_main(const float* __restrict__ pred,
                                              const float* __restrict__ targ,
                                              const float* __restrict__ thr,
                                              double* __restrict__ acc) {
    const int ch = blockIdx.x >> 8;
    const int blk = blockIdx.x & (BPC - 1);
    const size_t base = ((size_t)ch << CH_SHIFT) + (size_t)blk * BLK_ELEMS;
    const float4* p4 = (const float4*)(pred + base);
    const float4* t4 = (const float4*)(targ + base);
    const float th = thr[ch];
    float mse = 0.f, msk = 0.f, fg = 0.f, inter = 0.f, ssum = 0.f;
    for (int it = 0; it < BLK_ELEMS / (256 * 4); ++it) {
        float4 p = p4[it * 256 + threadIdx.x];
        float4 t = t4[it * 256 + threadIdx.x];
        float px[4] = {p.x, p.y, p.z, p.w};
        float tx[4] = {t.x, t.y, t.z, t.w};
        for (int j = 0; j < 4; ++j) {
            float d = px[j] - tx[j];
            float e = d * d;
            float m = (tx[j] >= th) ? 1.0f : 0.0f;
            mse += e;
            msk += e * m;
            fg += m;
            float s = soft_sig(px[j]);
            ssum += s;
            inter += s * m;
        }
    }
    double v0 = mse, v1 = msk, v2 = fg, v3 = inter, v4 = ssum;
    for (int off = 32; off; off >>= 1) {
        v0 += __shfl_down(v0, off);
        v1 += __shfl_down(v1, off);
        v2 += __shfl_down(v2, off);
        v3 += __shfl_down(v3, off);
        v4 += __shfl_down(v4, off);
    }
    __shared__ double s[4][5];
    const int wave = threadIdx.x >> 6, lane = threadIdx.x & 63;
    if (lane == 0) { s[wave][0] = v0; s[wave][1] = v1; s[wave][2] = v2; s[wave][3] = v3; s[wave][4] = v4; }
    __syncthreads();
    if (threadIdx.x == 0) {
        double a0 = s[0][0] + s[1][0] + s[2][0] + s[3][0];
        double a1 = s[0][1] + s[1][1] + s[2][1] + s[3][1];
        double a2 = s[0][2] + s[1][2] + s[2][2] + s[3][2];
        double a3 = s[0][3] + s[1][3] + s[2][3] + s[3][3];
        double a4 = s[0][4] + s[1][4] + s[2][4] + s[3][4];
        atomicAdd(&acc[ch * 5 + 0], a0);
        atomicAdd(&acc[ch * 5 + 1], a1);
        atomicAdd(&acc[ch * 5 + 2], a2);
        atomicAdd(&acc[ch * 5 + 3], a3);
        atomicAdd(&acc[ch * 5 + 4], a4);
    }
}

__global__ void k_final(const double* __restrict__ acc, float* __restrict__ out) {
    if (threadIdx.x != 0 || blockIdx.x != 0) return;
    float mse_sum = 0.0f, dice_sum = 0.0f;
    int nm = 0;
    for (int ch = 0; ch < CH; ++ch) {
        double mse = acc[ch * 5 + 0];
        double msk = acc[ch * 5 + 1];
        double fg  = acc[ch * 5 + 2];
        double itr = acc[ch * 5 + 3];
        double ss  = acc[ch * 5 + 4];
        bool has = fg > 0.0;
        float channel_mse = has ? (float)(msk / (fg + EPS_F))
                                : (float)(mse / (double)CH_ELEMS);
        mse_sum += channel_mse;
        float channel_dice = 1.0f - (float)(2.0 * itr / (ss + fg + EPS_F));
        if (has) { dice_sum += channel_dice; nm++; }
    }
    float masked_mse = mse_sum / (float)CH;
    float dice = (nm > 0) ? (dice_sum / (float)nm) : 0.0f;
    out[0] = 0.5f * masked_mse + 0.5f * dice;
}

extern "C" void kernel_launch(void* const* d_in, const int* in_sizes, int n_in,
                              void* d_out, int out_size, void* d_ws, size_t ws_size,
                              hipStream_t stream) {
    const float* pred = (const float*)d_in[0];
    const float* targ = (const float*)d_in[1];
    float* out = (float*)d_out;

    unsigned char* ws = (unsigned char*)d_ws;
    unsigned* minM = (unsigned*)ws;                    // 8 * 4 = 32 B
    unsigned* maxM = minM + CH;                        // 32 B
    unsigned* hist = maxM + CH;                        // 8 * 256 * 4 = 8192 B
    float*    thr  = (float*)(hist + CH * NB);         // 32 B  (offset 8256)
    double*   acc  = (double*)(ws + 8288);             // 8-aligned, 8*5*8 = 320 B

    const int grid = CH * BPC;                         // 2048 blocks

    k_init<<<8, 256, 0, stream>>>(minM, maxM, hist, acc);
    k_minmax<<<grid, 256, 0, stream>>>(targ, minM, maxM);
    k_hist<<<grid, 256, 0, stream>>>(targ, minM, maxM, hist);
    k_otsu<<<1, 64, 0, stream>>>(hist, minM, maxM, thr);
    k_main<<<grid, 256, 0, stream>>>(pred, targ, thr, acc);
    k_final<<<1, 64, 0, stream>>>(acc, out);
}